// Round 14
// baseline (82.225 us; speedup 1.0000x reference)
//
#include <hip/hip_runtime.h>
#include <hip/hip_bf16.h>
#include <math.h>

#define N_ROWS 4096
#define D 512
#define TWO_N 8192
#define TILE 128
#define NKT 4                /* 512 / 128 K-tiles */
#define NJB 64               /* 8192 / 128 column blocks */
#define NPAIRS 2080          /* 64*65/2 upper-tri blocks */
#define INV_T 5.0f

typedef __attribute__((ext_vector_type(4))) int i32x4;
typedef __attribute__((ext_vector_type(8))) int i32x8;
typedef __attribute__((ext_vector_type(2))) float f32x2;
typedef __attribute__((ext_vector_type(4))) float f32x4;
#define AS1 __attribute__((address_space(1)))
#define AS3 __attribute__((address_space(3)))

// ---------------- block reduction helper (broadcasts result) ----------------
template<int K>
__device__ inline void block_reduce_bcast(float (&v)[K]) {
  __shared__ float red[4][K];
  const int t = threadIdx.x;
  #pragma unroll
  for (int off = 32; off; off >>= 1)
    #pragma unroll
    for (int i = 0; i < K; ++i) v[i] += __shfl_xor(v[i], off, 64);
  __syncthreads();
  if ((t & 63) == 0)
    #pragma unroll
    for (int i = 0; i < K; ++i) red[t >> 6][i] = v[i];
  __syncthreads();
  #pragma unroll
  for (int i = 0; i < K; ++i) v[i] = red[0][i] + red[1][i] + red[2][i] + red[3][i];
}

// ---------------- kernel 1: wave-per-row normalize -> fp8 e4m3 reps --------
__global__ __launch_bounds__(256) void normalize_kernel(
    const float* __restrict__ ei_, const float* __restrict__ ej_,
    const float* __restrict__ ek_,
    unsigned char* __restrict__ rep8, float* __restrict__ diagexp,
    float* __restrict__ pos_ij, float* __restrict__ exp_ik)
{
  const int t = threadIdx.x;
  const int l = t & 63;
  const int n = blockIdx.x * 4 + (t >> 6);
  const long base = (long)n * D + l * 8;

  float ai[8], aj[8], ak[8];
  #pragma unroll
  for (int h = 0; h < 2; ++h) {
    const float4 vi = *reinterpret_cast<const float4*>(ei_ + base + h * 4);
    const float4 vj = *reinterpret_cast<const float4*>(ej_ + base + h * 4);
    const float4 vk = *reinterpret_cast<const float4*>(ek_ + base + h * 4);
    ai[h*4+0]=vi.x; ai[h*4+1]=vi.y; ai[h*4+2]=vi.z; ai[h*4+3]=vi.w;
    aj[h*4+0]=vj.x; aj[h*4+1]=vj.y; aj[h*4+2]=vj.z; aj[h*4+3]=vj.w;
    ak[h*4+0]=vk.x; ak[h*4+1]=vk.y; ak[h*4+2]=vk.z; ak[h*4+3]=vk.w;
  }

  float v[5] = {0.f, 0.f, 0.f, 0.f, 0.f};
  #pragma unroll
  for (int j = 0; j < 8; ++j) {
    v[0] += ai[j] * ai[j];
    v[1] += aj[j] * aj[j];
    v[2] += ak[j] * ak[j];
    v[3] += ai[j] * aj[j];
    v[4] += ak[j] * ai[j];
  }
  #pragma unroll
  for (int off = 32; off; off >>= 1)
    #pragma unroll
    for (int i = 0; i < 5; ++i) v[i] += __shfl_xor(v[i], off, 64);

  const float ni = fmaxf(sqrtf(v[0]), 1e-12f);
  const float nj = fmaxf(sqrtf(v[1]), 1e-12f);
  const float nk = fmaxf(sqrtf(v[2]), 1e-12f);
  const float invi = 1.0f / ni, invj = 1.0f / nj;

  float zi[8], zj[8];
  #pragma unroll
  for (int j = 0; j < 8; ++j) { zi[j] = ai[j] * invi; zj[j] = aj[j] * invj; }
  int wi0 = __builtin_amdgcn_cvt_pk_fp8_f32(zi[0], zi[1], 0, false);
  wi0     = __builtin_amdgcn_cvt_pk_fp8_f32(zi[2], zi[3], wi0, true);
  int wi1 = __builtin_amdgcn_cvt_pk_fp8_f32(zi[4], zi[5], 0, false);
  wi1     = __builtin_amdgcn_cvt_pk_fp8_f32(zi[6], zi[7], wi1, true);
  int wj0 = __builtin_amdgcn_cvt_pk_fp8_f32(zj[0], zj[1], 0, false);
  wj0     = __builtin_amdgcn_cvt_pk_fp8_f32(zj[2], zj[3], wj0, true);
  int wj1 = __builtin_amdgcn_cvt_pk_fp8_f32(zj[4], zj[5], 0, false);
  wj1     = __builtin_amdgcn_cvt_pk_fp8_f32(zj[6], zj[7], wj1, true);
  int2 pi; pi.x = wi0; pi.y = wi1;
  int2 pj; pj.x = wj0; pj.y = wj1;
  *reinterpret_cast<int2*>(rep8 + base) = pi;
  *reinterpret_cast<int2*>(rep8 + (long)N_ROWS * D + base) = pj;

  // diag = sum of squares of the DEQUANTIZED values (matches MFMA diagonal)
  float q[2] = {0.f, 0.f};
  #pragma unroll
  for (int h = 0; h < 2; ++h) {
    const int wi = h ? wi1 : wi0, wj = h ? wj1 : wj0;
    const f32x2 d0 = __builtin_amdgcn_cvt_pk_f32_fp8(wi, false);
    const f32x2 d1 = __builtin_amdgcn_cvt_pk_f32_fp8(wi, true);
    const f32x2 e0 = __builtin_amdgcn_cvt_pk_f32_fp8(wj, false);
    const f32x2 e1 = __builtin_amdgcn_cvt_pk_f32_fp8(wj, true);
    q[0] += d0.x*d0.x + d0.y*d0.y + d1.x*d1.x + d1.y*d1.y;
    q[1] += e0.x*e0.x + e0.y*e0.y + e1.x*e1.x + e1.y*e1.y;
  }
  #pragma unroll
  for (int off = 32; off; off >>= 1)
    #pragma unroll
    for (int i = 0; i < 2; ++i) q[i] += __shfl_xor(q[i], off, 64);

  if (l == 0) {
    diagexp[n]          = __expf(INV_T * q[0]);
    diagexp[N_ROWS + n] = __expf(INV_T * q[1]);
    pos_ij[n] = v[3] / (ni * nj);
    exp_ik[n] = __expf(INV_T * v[4] / (nk * ni));
  }
}

// ---------------- kernel 2: reduce the two scalars --------------------------
__global__ __launch_bounds__(256) void scalar_kernel(
    const float* __restrict__ pos_ij, const float* __restrict__ exp_ik,
    float* __restrict__ scalars)
{
  const int t = threadIdx.x;
  float v[2] = {0.f, 0.f};
  for (int i = t; i < N_ROWS; i += 256) { v[0] += pos_ij[i]; v[1] += exp_ik[i]; }
  block_reduce_bcast<2>(v);
  if (t == 0) { scalars[0] = v[0]; scalars[1] = v[1]; }
}

// ---------------- kernel 3: 128^2 MX-fp8 K=128, 8 waves, 32KB, hi-TLP ------
// R12 datapath + 512-thread blocks: 8 waves (wm2 x wn4, per-wave 64x32 out,
// acc[4][2] = 32 VGPR) -> 3-4 co-resident blocks/CU = 24-32 waves. One
// block's stage+drain hides under other blocks' MFMA (the only lever that
// has moved time all session). Single 32KB buffer, 2 barriers/K-tile.
// launch_bounds(512,6): VGPR cap 85 (R10 spill detector: WRITE_SIZE ~2MB).
// Row = 128B = 8 slots of 16B; swizzle slot^(row&7); inverse on source.
__device__ __forceinline__ void stage128(
    const unsigned char* __restrict__ rep8, char* region,
    long R0, int kt, int t)
{
  #pragma unroll
  for (int s = 0; s < 2; ++s) {
    const int cc = s * 512 + t;          // chunk 0..1023
    const int row = cc >> 3, slot = cc & 7;
    const int sg = slot ^ (row & 7);     // inverse-swizzled source slot
    const unsigned char* g = rep8 + (R0 + row) * D + kt * 128 + sg * 16;
    __builtin_amdgcn_global_load_lds((const AS1 void*)g,
        (AS3 void*)(region + cc * 16), 16, 0, 0);
  }
}

__global__ __launch_bounds__(512, 6) void gemm_expsum_kernel(
    const unsigned char* __restrict__ rep8, float* __restrict__ S_partial)
{
  __shared__ __align__(16) char smem[32768];   // A 16K | B 16K

  const int t = threadIdx.x;
  const int l = t & 63;
  const int w = t >> 6;          // wave 0..7
  const int wm = w >> 2;         // row half 0..1 (64 rows)
  const int wn = w & 3;          // col quarter 0..3 (32 cols)
  const int s4 = l >> 4;         // k-group 0..3

  // XCD-aware bijective swizzle (2080 = 8*260), then triangular decode I<=J
  const int wg = (blockIdx.x & 7) * 260 + (blockIdx.x >> 3);
  int k = wg, I = 0;
  while (k >= NJB - I) { k -= NJB - I; ++I; }
  const int J = I + k;
  const long rI = (long)I * TILE;
  const long cJ = (long)J * TILE;

  // fragment byte offsets: row*128 + ((2g+h)^(row&7))*16
  int a_off[4][2], b_off[2][2];
  #pragma unroll
  for (int mi = 0; mi < 4; ++mi) {
    const int r = wm * 64 + mi * 16 + (l & 15);
    #pragma unroll
    for (int h = 0; h < 2; ++h)
      a_off[mi][h] = r * 128 + (((s4 * 2 + h) ^ (r & 7)) * 16);
  }
  #pragma unroll
  for (int ni = 0; ni < 2; ++ni) {
    const int r = wn * 32 + ni * 16 + (l & 15);
    #pragma unroll
    for (int h = 0; h < 2; ++h)
      b_off[ni][h] = 16384 + r * 128 + (((s4 * 2 + h) ^ (r & 7)) * 16);
  }

  f32x4 acc[4][2];
  #pragma unroll
  for (int a = 0; a < 4; ++a)
    #pragma unroll
    for (int b = 0; b < 2; ++b) { f32x4 z = {0.f, 0.f, 0.f, 0.f}; acc[a][b] = z; }

  for (int kt = 0; kt < NKT; ++kt) {
    if (kt) __syncthreads();             // everyone done reading prev tile
    stage128(rep8, smem, rI, kt, t);
    stage128(rep8, smem + 16384, cJ, kt, t);
    __syncthreads();                     // drains vmcnt(0): tile landed

    i32x8 bf[2];
    #pragma unroll
    for (int ni = 0; ni < 2; ++ni) {
      const i32x4 lo = *reinterpret_cast<const i32x4*>(smem + b_off[ni][0]);
      const i32x4 hi = *reinterpret_cast<const i32x4*>(smem + b_off[ni][1]);
      bf[ni] = __builtin_shufflevector(lo, hi, 0, 1, 2, 3, 4, 5, 6, 7);
    }
    __builtin_amdgcn_s_setprio(1);
    #pragma unroll
    for (int mi = 0; mi < 4; ++mi) {
      const i32x4 lo = *reinterpret_cast<const i32x4*>(smem + a_off[mi][0]);
      const i32x4 hi = *reinterpret_cast<const i32x4*>(smem + a_off[mi][1]);
      const i32x8 af = __builtin_shufflevector(lo, hi, 0, 1, 2, 3, 4, 5, 6, 7);
      #pragma unroll
      for (int ni = 0; ni < 2; ++ni)
        acc[mi][ni] = __builtin_amdgcn_mfma_scale_f32_16x16x128_f8f6f4(
            af, bf[ni], acc[mi][ni], 0 /*A fmt fp8*/, 0 /*B fmt fp8*/,
            0, 0x7F7F7F7F, 0, 0x7F7F7F7F);
    }
    __builtin_amdgcn_s_setprio(0);
  }
  __syncthreads();                       // all ds_reads retired: smem reusable
  float* rowbuf = (float*)smem;          // [4 wn][128]
  float* colbuf = (float*)(smem + 2048); // [2 wm][128]

  // epilogue: e = exp(5*sim); row-sums (rows of I) and col-sums (symmetry)
  // C/D layout shape-determined: col=l&15, row=(l>>4)*4+j
  float rsum[4][4], csum[2];
  #pragma unroll
  for (int mi = 0; mi < 4; ++mi)
    #pragma unroll
    for (int j = 0; j < 4; ++j) rsum[mi][j] = 0.f;
  csum[0] = csum[1] = 0.f;

  #pragma unroll
  for (int mi = 0; mi < 4; ++mi)
    #pragma unroll
    for (int ni = 0; ni < 2; ++ni)
      #pragma unroll
      for (int j = 0; j < 4; ++j) {
        const float e = __expf(INV_T * acc[mi][ni][j]);
        rsum[mi][j] += e;
        csum[ni]   += e;
      }

  #pragma unroll
  for (int mi = 0; mi < 4; ++mi) {
    #pragma unroll
    for (int off = 1; off < 16; off <<= 1)
      #pragma unroll
      for (int j = 0; j < 4; ++j) rsum[mi][j] += __shfl_xor(rsum[mi][j], off, 64);
    if ((l & 15) == 0) {
      const int rloc = wm * 64 + mi * 16 + s4 * 4;
      #pragma unroll
      for (int j = 0; j < 4; ++j) rowbuf[wn * TILE + rloc + j] = rsum[mi][j];
    }
  }
  #pragma unroll
  for (int off = 16; off < 64; off <<= 1)
    #pragma unroll
    for (int ni = 0; ni < 2; ++ni) csum[ni] += __shfl_xor(csum[ni], off, 64);
  if (l < 16) {
    #pragma unroll
    for (int ni = 0; ni < 2; ++ni)
      colbuf[wm * TILE + wn * 32 + ni * 16 + l] = csum[ni];
  }
  __syncthreads();

  if (t < TILE) {
    S_partial[(long)J * TWO_N + rI + t] =
        rowbuf[t] + rowbuf[TILE + t] + rowbuf[2 * TILE + t] + rowbuf[3 * TILE + t];
  } else if (t < 2 * TILE && I != J) {
    const int c = t - TILE;
    S_partial[(long)I * TWO_N + cJ + c] = colbuf[c] + colbuf[TILE + c];
  }
}

// ---------------- kernel 4: per-row log(denominator), block partials -------
__global__ __launch_bounds__(256) void rowlog_kernel(
    const float* __restrict__ S_partial, const float* __restrict__ diagexp,
    const float* __restrict__ scalars, float* __restrict__ blockpart)
{
  const int t = threadIdx.x;
  const int r = blockIdx.x * 256 + t;
  float s = 0.f;
  #pragma unroll 8
  for (int Jb = 0; Jb < NJB; ++Jb) s += S_partial[(long)Jb * TWO_N + r];
  const float denom_fu = 2.0f * scalars[1];
  float v[1];
  v[0] = logf(s - diagexp[r] + denom_fu);
  block_reduce_bcast<1>(v);
  if (t == 0) blockpart[blockIdx.x] = v[0];
}

// ---------------- kernel 5: final scalar -----------------------------------
__global__ void final_kernel(const float* __restrict__ blockpart,
                             const float* __restrict__ scalars,
                             float* __restrict__ out)
{
  const int t = threadIdx.x;   // 64 threads
  float s = (t < TWO_N / 256) ? blockpart[t] : 0.f;
  #pragma unroll
  for (int off = 32; off; off >>= 1) s += __shfl_xor(s, off, 64);
  if (t == 0) out[0] = (s - 10.0f * scalars[0]) / (float)TWO_N;
}

extern "C" void kernel_launch(void* const* d_in, const int* in_sizes, int n_in,
                              void* d_out, int out_size, void* d_ws, size_t ws_size,
                              hipStream_t stream)
{
  const float* ei = (const float*)d_in[0];
  const float* ej = (const float*)d_in[1];
  const float* ek = (const float*)d_in[2];
  float* out = (float*)d_out;

  char* ws = (char*)d_ws;
  unsigned char* rep8 = (unsigned char*)ws;                            // 4 MB
  float* S_partial = (float*)(ws + 4u * 1024 * 1024);                  // 2 MB
  float* diagexp   = (float*)(ws + 6u * 1024 * 1024);                  // 32 KB
  float* pos_ij    = (float*)(ws + 6u * 1024 * 1024 + 32 * 1024);      // 16 KB
  float* exp_ik    = (float*)(ws + 6u * 1024 * 1024 + 48 * 1024);      // 16 KB
  float* scalars   = (float*)(ws + 6u * 1024 * 1024 + 64 * 1024);      // 8 B
  float* blockpart = (float*)(ws + 6u * 1024 * 1024 + 64 * 1024 + 256); // 128 B

  normalize_kernel<<<N_ROWS / 4, 256, 0, stream>>>(ei, ej, ek, rep8, diagexp,
                                                   pos_ij, exp_ik);
  scalar_kernel<<<1, 256, 0, stream>>>(pos_ij, exp_ik, scalars);
  gemm_expsum_kernel<<<NPAIRS, 512, 0, stream>>>(rep8, S_partial);
  rowlog_kernel<<<TWO_N / 256, 256, 0, stream>>>(S_partial, diagexp, scalars,
                                                 blockpart);
  final_kernel<<<1, 64, 0, stream>>>(blockpart, scalars, out);
}

// Round 15
// 63.245 us; speedup vs baseline: 1.3001x; 1.3001x over previous
//
#include <hip/hip_runtime.h>
#include <hip/hip_bf16.h>
#include <math.h>

#define N_ROWS 4096
#define D 512
#define TWO_N 8192
#define TILE 128
#define NKT 4                /* 512 / 128 K-tiles */
#define NJB 64               /* 8192 / 128 column blocks */
#define NPAIRS 2080          /* 64*65/2 upper-tri blocks */
#define INV_T 5.0f

typedef __attribute__((ext_vector_type(4))) int i32x4;
typedef __attribute__((ext_vector_type(8))) int i32x8;
typedef __attribute__((ext_vector_type(2))) float f32x2;
typedef __attribute__((ext_vector_type(4))) float f32x4;
#define AS1 __attribute__((address_space(1)))
#define AS3 __attribute__((address_space(3)))

// ---------------- block reduction helper (broadcasts result) ----------------
template<int K>
__device__ inline void block_reduce_bcast(float (&v)[K]) {
  __shared__ float red[4][K];
  const int t = threadIdx.x;
  #pragma unroll
  for (int off = 32; off; off >>= 1)
    #pragma unroll
    for (int i = 0; i < K; ++i) v[i] += __shfl_xor(v[i], off, 64);
  __syncthreads();
  if ((t & 63) == 0)
    #pragma unroll
    for (int i = 0; i < K; ++i) red[t >> 6][i] = v[i];
  __syncthreads();
  #pragma unroll
  for (int i = 0; i < K; ++i) v[i] = red[0][i] + red[1][i] + red[2][i] + red[3][i];
}

// ---------------- kernel 1: wave-per-row normalize -> fp8 e4m3 reps --------
__global__ __launch_bounds__(256) void normalize_kernel(
    const float* __restrict__ ei_, const float* __restrict__ ej_,
    const float* __restrict__ ek_,
    unsigned char* __restrict__ rep8, float* __restrict__ diagexp,
    float* __restrict__ pos_ij, float* __restrict__ exp_ik)
{
  const int t = threadIdx.x;
  const int l = t & 63;
  const int n = blockIdx.x * 4 + (t >> 6);
  const long base = (long)n * D + l * 8;

  float ai[8], aj[8], ak[8];
  #pragma unroll
  for (int h = 0; h < 2; ++h) {
    const float4 vi = *reinterpret_cast<const float4*>(ei_ + base + h * 4);
    const float4 vj = *reinterpret_cast<const float4*>(ej_ + base + h * 4);
    const float4 vk = *reinterpret_cast<const float4*>(ek_ + base + h * 4);
    ai[h*4+0]=vi.x; ai[h*4+1]=vi.y; ai[h*4+2]=vi.z; ai[h*4+3]=vi.w;
    aj[h*4+0]=vj.x; aj[h*4+1]=vj.y; aj[h*4+2]=vj.z; aj[h*4+3]=vj.w;
    ak[h*4+0]=vk.x; ak[h*4+1]=vk.y; ak[h*4+2]=vk.z; ak[h*4+3]=vk.w;
  }

  float v[5] = {0.f, 0.f, 0.f, 0.f, 0.f};
  #pragma unroll
  for (int j = 0; j < 8; ++j) {
    v[0] += ai[j] * ai[j];
    v[1] += aj[j] * aj[j];
    v[2] += ak[j] * ak[j];
    v[3] += ai[j] * aj[j];
    v[4] += ak[j] * ai[j];
  }
  #pragma unroll
  for (int off = 32; off; off >>= 1)
    #pragma unroll
    for (int i = 0; i < 5; ++i) v[i] += __shfl_xor(v[i], off, 64);

  const float ni = fmaxf(sqrtf(v[0]), 1e-12f);
  const float nj = fmaxf(sqrtf(v[1]), 1e-12f);
  const float nk = fmaxf(sqrtf(v[2]), 1e-12f);
  const float invi = 1.0f / ni, invj = 1.0f / nj;

  float zi[8], zj[8];
  #pragma unroll
  for (int j = 0; j < 8; ++j) { zi[j] = ai[j] * invi; zj[j] = aj[j] * invj; }
  int wi0 = __builtin_amdgcn_cvt_pk_fp8_f32(zi[0], zi[1], 0, false);
  wi0     = __builtin_amdgcn_cvt_pk_fp8_f32(zi[2], zi[3], wi0, true);
  int wi1 = __builtin_amdgcn_cvt_pk_fp8_f32(zi[4], zi[5], 0, false);
  wi1     = __builtin_amdgcn_cvt_pk_fp8_f32(zi[6], zi[7], wi1, true);
  int wj0 = __builtin_amdgcn_cvt_pk_fp8_f32(zj[0], zj[1], 0, false);
  wj0     = __builtin_amdgcn_cvt_pk_fp8_f32(zj[2], zj[3], wj0, true);
  int wj1 = __builtin_amdgcn_cvt_pk_fp8_f32(zj[4], zj[5], 0, false);
  wj1     = __builtin_amdgcn_cvt_pk_fp8_f32(zj[6], zj[7], wj1, true);
  int2 pi; pi.x = wi0; pi.y = wi1;
  int2 pj; pj.x = wj0; pj.y = wj1;
  *reinterpret_cast<int2*>(rep8 + base) = pi;
  *reinterpret_cast<int2*>(rep8 + (long)N_ROWS * D + base) = pj;

  // diag = sum of squares of the DEQUANTIZED values (matches MFMA diagonal)
  float q[2] = {0.f, 0.f};
  #pragma unroll
  for (int h = 0; h < 2; ++h) {
    const int wi = h ? wi1 : wi0, wj = h ? wj1 : wj0;
    const f32x2 d0 = __builtin_amdgcn_cvt_pk_f32_fp8(wi, false);
    const f32x2 d1 = __builtin_amdgcn_cvt_pk_f32_fp8(wi, true);
    const f32x2 e0 = __builtin_amdgcn_cvt_pk_f32_fp8(wj, false);
    const f32x2 e1 = __builtin_amdgcn_cvt_pk_f32_fp8(wj, true);
    q[0] += d0.x*d0.x + d0.y*d0.y + d1.x*d1.x + d1.y*d1.y;
    q[1] += e0.x*e0.x + e0.y*e0.y + e1.x*e1.x + e1.y*e1.y;
  }
  #pragma unroll
  for (int off = 32; off; off >>= 1)
    #pragma unroll
    for (int i = 0; i < 2; ++i) q[i] += __shfl_xor(q[i], off, 64);

  if (l == 0) {
    diagexp[n]          = __expf(INV_T * q[0]);
    diagexp[N_ROWS + n] = __expf(INV_T * q[1]);
    pos_ij[n] = v[3] / (ni * nj);
    exp_ik[n] = __expf(INV_T * v[4] / (nk * ni));
  }
}

// ---------------- kernel 2: reduce the two scalars --------------------------
__global__ __launch_bounds__(256) void scalar_kernel(
    const float* __restrict__ pos_ij, const float* __restrict__ exp_ik,
    float* __restrict__ scalars)
{
  const int t = threadIdx.x;
  float v[2] = {0.f, 0.f};
  for (int i = t; i < N_ROWS; i += 256) { v[0] += pos_ij[i]; v[1] += exp_ik[i]; }
  block_reduce_bcast<2>(v);
  if (t == 0) { scalars[0] = v[0]; scalars[1] = v[1]; }
}

// ---------------- kernel 3: 128^2 MX-fp8 K=128, 8 waves, 32KB, hi-TLP ------
// R14 structure (8 waves wm2 x wn4, per-wave 64x32 out, single 32KB buffer,
// 2 barriers/K-tile) with NATURAL register allocation: __launch_bounds__(512)
// only. R14's (512,6) set the VGPR cap exactly at the kernel's need (~85) ->
// allocator thrashed to VGPR 40 + 127MB spill. Never set min-waves near the
// boundary. Natural ~85-95 VGPR -> 5-6 waves/SIMD -> ~3 blocks x 8 waves/CU.
// Row = 128B = 8 slots of 16B; swizzle slot^(row&7); inverse on source.
__device__ __forceinline__ void stage128(
    const unsigned char* __restrict__ rep8, char* region,
    long R0, int kt, int t)
{
  #pragma unroll
  for (int s = 0; s < 2; ++s) {
    const int cc = s * 512 + t;          // chunk 0..1023
    const int row = cc >> 3, slot = cc & 7;
    const int sg = slot ^ (row & 7);     // inverse-swizzled source slot
    const unsigned char* g = rep8 + (R0 + row) * D + kt * 128 + sg * 16;
    __builtin_amdgcn_global_load_lds((const AS1 void*)g,
        (AS3 void*)(region + cc * 16), 16, 0, 0);
  }
}

__global__ __launch_bounds__(512) void gemm_expsum_kernel(
    const unsigned char* __restrict__ rep8, float* __restrict__ S_partial)
{
  __shared__ __align__(16) char smem[32768];   // A 16K | B 16K

  const int t = threadIdx.x;
  const int l = t & 63;
  const int w = t >> 6;          // wave 0..7
  const int wm = w >> 2;         // row half 0..1 (64 rows)
  const int wn = w & 3;          // col quarter 0..3 (32 cols)
  const int s4 = l >> 4;         // k-group 0..3

  // XCD-aware bijective swizzle (2080 = 8*260), then triangular decode I<=J
  const int wg = (blockIdx.x & 7) * 260 + (blockIdx.x >> 3);
  int k = wg, I = 0;
  while (k >= NJB - I) { k -= NJB - I; ++I; }
  const int J = I + k;
  const long rI = (long)I * TILE;
  const long cJ = (long)J * TILE;

  // fragment byte offsets: row*128 + ((2g+h)^(row&7))*16
  int a_off[4][2], b_off[2][2];
  #pragma unroll
  for (int mi = 0; mi < 4; ++mi) {
    const int r = wm * 64 + mi * 16 + (l & 15);
    #pragma unroll
    for (int h = 0; h < 2; ++h)
      a_off[mi][h] = r * 128 + (((s4 * 2 + h) ^ (r & 7)) * 16);
  }
  #pragma unroll
  for (int ni = 0; ni < 2; ++ni) {
    const int r = wn * 32 + ni * 16 + (l & 15);
    #pragma unroll
    for (int h = 0; h < 2; ++h)
      b_off[ni][h] = 16384 + r * 128 + (((s4 * 2 + h) ^ (r & 7)) * 16);
  }

  f32x4 acc[4][2];
  #pragma unroll
  for (int a = 0; a < 4; ++a)
    #pragma unroll
    for (int b = 0; b < 2; ++b) { f32x4 z = {0.f, 0.f, 0.f, 0.f}; acc[a][b] = z; }

  for (int kt = 0; kt < NKT; ++kt) {
    if (kt) __syncthreads();             // everyone done reading prev tile
    stage128(rep8, smem, rI, kt, t);
    stage128(rep8, smem + 16384, cJ, kt, t);
    __syncthreads();                     // drains vmcnt(0): tile landed

    i32x8 bf[2];
    #pragma unroll
    for (int ni = 0; ni < 2; ++ni) {
      const i32x4 lo = *reinterpret_cast<const i32x4*>(smem + b_off[ni][0]);
      const i32x4 hi = *reinterpret_cast<const i32x4*>(smem + b_off[ni][1]);
      bf[ni] = __builtin_shufflevector(lo, hi, 0, 1, 2, 3, 4, 5, 6, 7);
    }
    __builtin_amdgcn_s_setprio(1);
    #pragma unroll
    for (int mi = 0; mi < 4; ++mi) {
      const i32x4 lo = *reinterpret_cast<const i32x4*>(smem + a_off[mi][0]);
      const i32x4 hi = *reinterpret_cast<const i32x4*>(smem + a_off[mi][1]);
      const i32x8 af = __builtin_shufflevector(lo, hi, 0, 1, 2, 3, 4, 5, 6, 7);
      #pragma unroll
      for (int ni = 0; ni < 2; ++ni)
        acc[mi][ni] = __builtin_amdgcn_mfma_scale_f32_16x16x128_f8f6f4(
            af, bf[ni], acc[mi][ni], 0 /*A fmt fp8*/, 0 /*B fmt fp8*/,
            0, 0x7F7F7F7F, 0, 0x7F7F7F7F);
    }
    __builtin_amdgcn_s_setprio(0);
  }
  __syncthreads();                       // all ds_reads retired: smem reusable
  float* rowbuf = (float*)smem;          // [4 wn][128]
  float* colbuf = (float*)(smem + 2048); // [2 wm][128]

  // epilogue: e = exp(5*sim); row-sums (rows of I) and col-sums (symmetry)
  // C/D layout shape-determined: col=l&15, row=(l>>4)*4+j
  float rsum[4][4], csum[2];
  #pragma unroll
  for (int mi = 0; mi < 4; ++mi)
    #pragma unroll
    for (int j = 0; j < 4; ++j) rsum[mi][j] = 0.f;
  csum[0] = csum[1] = 0.f;

  #pragma unroll
  for (int mi = 0; mi < 4; ++mi)
    #pragma unroll
    for (int ni = 0; ni < 2; ++ni)
      #pragma unroll
      for (int j = 0; j < 4; ++j) {
        const float e = __expf(INV_T * acc[mi][ni][j]);
        rsum[mi][j] += e;
        csum[ni]   += e;
      }

  #pragma unroll
  for (int mi = 0; mi < 4; ++mi) {
    #pragma unroll
    for (int off = 1; off < 16; off <<= 1)
      #pragma unroll
      for (int j = 0; j < 4; ++j) rsum[mi][j] += __shfl_xor(rsum[mi][j], off, 64);
    if ((l & 15) == 0) {
      const int rloc = wm * 64 + mi * 16 + s4 * 4;
      #pragma unroll
      for (int j = 0; j < 4; ++j) rowbuf[wn * TILE + rloc + j] = rsum[mi][j];
    }
  }
  #pragma unroll
  for (int off = 16; off < 64; off <<= 1)
    #pragma unroll
    for (int ni = 0; ni < 2; ++ni) csum[ni] += __shfl_xor(csum[ni], off, 64);
  if (l < 16) {
    #pragma unroll
    for (int ni = 0; ni < 2; ++ni)
      colbuf[wm * TILE + wn * 32 + ni * 16 + l] = csum[ni];
  }
  __syncthreads();

  if (t < TILE) {
    S_partial[(long)J * TWO_N + rI + t] =
        rowbuf[t] + rowbuf[TILE + t] + rowbuf[2 * TILE + t] + rowbuf[3 * TILE + t];
  } else if (t < 2 * TILE && I != J) {
    const int c = t - TILE;
    S_partial[(long)I * TWO_N + cJ + c] = colbuf[c] + colbuf[TILE + c];
  }
}

// ---------------- kernel 4: per-row log(denominator), block partials -------
__global__ __launch_bounds__(256) void rowlog_kernel(
    const float* __restrict__ S_partial, const float* __restrict__ diagexp,
    const float* __restrict__ scalars, float* __restrict__ blockpart)
{
  const int t = threadIdx.x;
  const int r = blockIdx.x * 256 + t;
  float s = 0.f;
  #pragma unroll 8
  for (int Jb = 0; Jb < NJB; ++Jb) s += S_partial[(long)Jb * TWO_N + r];
  const float denom_fu = 2.0f * scalars[1];
  float v[1];
  v[0] = logf(s - diagexp[r] + denom_fu);
  block_reduce_bcast<1>(v);
  if (t == 0) blockpart[blockIdx.x] = v[0];
}

// ---------------- kernel 5: final scalar -----------------------------------
__global__ void final_kernel(const float* __restrict__ blockpart,
                             const float* __restrict__ scalars,
                             float* __restrict__ out)
{
  const int t = threadIdx.x;   // 64 threads
  float s = (t < TWO_N / 256) ? blockpart[t] : 0.f;
  #pragma unroll
  for (int off = 32; off; off >>= 1) s += __shfl_xor(s, off, 64);
  if (t == 0) out[0] = (s - 10.0f * scalars[0]) / (float)TWO_N;
}

extern "C" void kernel_launch(void* const* d_in, const int* in_sizes, int n_in,
                              void* d_out, int out_size, void* d_ws, size_t ws_size,
                              hipStream_t stream)
{
  const float* ei = (const float*)d_in[0];
  const float* ej = (const float*)d_in[1];
  const float* ek = (const float*)d_in[2];
  float* out = (float*)d_out;

  char* ws = (char*)d_ws;
  unsigned char* rep8 = (unsigned char*)ws;                            // 4 MB
  float* S_partial = (float*)(ws + 4u * 1024 * 1024);                  // 2 MB
  float* diagexp   = (float*)(ws + 6u * 1024 * 1024);                  // 32 KB
  float* pos_ij    = (float*)(ws + 6u * 1024 * 1024 + 32 * 1024);      // 16 KB
  float* exp_ik    = (float*)(ws + 6u * 1024 * 1024 + 48 * 1024);      // 16 KB
  float* scalars   = (float*)(ws + 6u * 1024 * 1024 + 64 * 1024);      // 8 B
  float* blockpart = (float*)(ws + 6u * 1024 * 1024 + 64 * 1024 + 256); // 128 B

  normalize_kernel<<<N_ROWS / 4, 256, 0, stream>>>(ei, ej, ek, rep8, diagexp,
                                                   pos_ij, exp_ik);
  scalar_kernel<<<1, 256, 0, stream>>>(pos_ij, exp_ik, scalars);
  gemm_expsum_kernel<<<NPAIRS, 512, 0, stream>>>(rep8, S_partial);
  rowlog_kernel<<<TWO_N / 256, 256, 0, stream>>>(S_partial, diagexp, scalars,
                                                 blockpart);
  final_kernel<<<1, 64, 0, stream>>>(blockpart, scalars, out);
}